// Round 6
// baseline (266.237 us; speedup 1.0000x reference)
//
#include <hip/hip_runtime.h>
#include <hip/hip_cooperative_groups.h>
#include <math.h>

namespace cg = cooperative_groups;

// B=4, N=1024, CQ=CH=512, H=8, D=64
// ws: qb bf16 4M | kb bf16 4M | vtb bf16 4M | gateb f32 8M | obb bf16 4M |
//     Xb bf16 4M | Wcat bf16 2.5M

typedef __bf16 bf16x8 __attribute__((ext_vector_type(8)));
typedef float f32x4 __attribute__((ext_vector_type(4)));

__device__ __forceinline__ unsigned short f2bf(float f) {
    union { float f; unsigned u; } v; v.f = f;
    unsigned r = v.u + 0x7fff + ((v.u >> 16) & 1);
    return (unsigned short)(r >> 16);
}

__device__ __forceinline__ bf16x8 ldb8(const unsigned short* p) {
    union { float4 f; bf16x8 b; } u;
    u.f = *(const float4*)p;
    return u.b;
}

#define GSTR 40   // GEMM LDS stride (ushorts): 80B rows, conflict-benign
#define LSTR 72   // attn LDS stride

// ===========================================================================
// FUSED cooperative kernel: 512 blocks x 256 threads, 4 phases + grid.sync.
// Phase 0: fp32->bf16 convert.  Phase 1: proj GEMM (q,k,gate,v).
// Phase 2: flash attention.     Phase 3: out GEMM + gate.
// ===========================================================================
__global__ __launch_bounds__(256, 2) void fused_kernel(
    const float* __restrict__ X, const float* __restrict__ bias,
    const float* __restrict__ Wq, const float* __restrict__ bq,
    const float* __restrict__ Wk, const float* __restrict__ Wv,
    const float* __restrict__ Wo, const float* __restrict__ bo,
    const float* __restrict__ Wg, const float* __restrict__ bg,
    const float* __restrict__ gbias, float* __restrict__ out,
    unsigned short* __restrict__ qb, unsigned short* __restrict__ kb,
    unsigned short* __restrict__ vtb, float* __restrict__ gateb,
    unsigned short* __restrict__ obb,
    unsigned short* __restrict__ Xb, unsigned short* __restrict__ Wcat)
{
    cg::grid_group grid = cg::this_grid();
    __shared__ __align__(16) unsigned short smem[14336];   // 28 KB union

    const int blk = blockIdx.x;
    const int tid = threadIdx.x;
    const int lane = tid & 63;
    const int quad = lane >> 4, lx = lane & 15;
    const int wid = tid >> 6;

    // ---------------- Phase 0: convert (grid-stride) ----------------
    {
        int idx = blk * 256 + tid;    // 131072 threads, 851968 float4-chunks
#pragma unroll 1
        for (int it = 0; it < 7; ++it) {
            int chunk = idx + it * 131072;
            if (chunk < 851968) {
                int i4 = chunk * 4;
                const float* src; unsigned short* dst; int off;
                if (i4 < 2097152) { src = X; dst = Xb; off = i4; }
                else {
                    int g = i4 - 2097152;
                    int sect = g >> 18;
                    src = (sect == 0) ? Wq : (sect == 1) ? Wk : (sect == 2) ? Wg
                        : (sect == 3) ? Wv : Wo;
                    dst = Wcat + (sect << 18);
                    off = g & 262143;
                }
                float4 v = *(const float4*)&src[off];
                ushort4 u;
                u.x = f2bf(v.x); u.y = f2bf(v.y); u.z = f2bf(v.z); u.w = f2bf(v.w);
                *(ushort4*)&dst[off] = u;
            }
        }
    }
    grid.sync();

    // ---------------- Phase 1: proj GEMM 128x128 ----------------
    {
        unsigned short* Ab = smem;               // 128*40
        unsigned short* Bb = smem + 128 * GSTR;  // 128*40
        const int row0 = (blk & 31) * 128;
        const int colv0 = (blk >> 5) * 128;
        const unsigned short* Ag = Xb + (size_t)row0 * 512;
        const unsigned short* Bg = Wcat + (size_t)colv0 * 512;
        const int mw0 = (wid >> 1) * 64, nw0 = (wid & 1) * 64;
        const int rA = tid >> 2, cA = (tid & 3) * 8;
        const int l0 = rA * GSTR + cA;
        const int l1 = (rA + 64) * GSTR + cA;

        f32x4 acc[4][4];
#pragma unroll
        for (int i = 0; i < 4; ++i)
#pragma unroll
            for (int j = 0; j < 4; ++j) acc[i][j] = (f32x4){0.f, 0.f, 0.f, 0.f};

        float4 a0 = *(const float4*)&Ag[(size_t)rA * 512 + cA];
        float4 a1 = *(const float4*)&Ag[(size_t)(rA + 64) * 512 + cA];
        float4 b0 = *(const float4*)&Bg[(size_t)rA * 512 + cA];
        float4 b1 = *(const float4*)&Bg[(size_t)(rA + 64) * 512 + cA];

#pragma unroll 1
        for (int k0 = 0; k0 < 512; k0 += 32) {
            *(float4*)&Ab[l0] = a0;
            *(float4*)&Ab[l1] = a1;
            *(float4*)&Bb[l0] = b0;
            *(float4*)&Bb[l1] = b1;
            __syncthreads();
            if (k0 < 480) {
                int kn = k0 + 32;
                a0 = *(const float4*)&Ag[(size_t)rA * 512 + kn + cA];
                a1 = *(const float4*)&Ag[(size_t)(rA + 64) * 512 + kn + cA];
                b0 = *(const float4*)&Bg[(size_t)rA * 512 + kn + cA];
                b1 = *(const float4*)&Bg[(size_t)(rA + 64) * 512 + kn + cA];
            }
            bf16x8 af[4], bfr[4];
#pragma unroll
            for (int mi = 0; mi < 4; ++mi)
                af[mi] = ldb8(&Ab[(mw0 + mi * 16 + lx) * GSTR + quad * 8]);
#pragma unroll
            for (int ni = 0; ni < 4; ++ni)
                bfr[ni] = ldb8(&Bb[(nw0 + ni * 16 + lx) * GSTR + quad * 8]);
#pragma unroll
            for (int mi = 0; mi < 4; ++mi)
#pragma unroll
                for (int ni = 0; ni < 4; ++ni)
                    acc[mi][ni] = __builtin_amdgcn_mfma_f32_16x16x32_bf16(
                        af[mi], bfr[ni], acc[mi][ni], 0, 0, 0);
            __syncthreads();
        }

        const int wsel = colv0 >> 9;
        const int ncb = colv0 & 511;
        if (wsel == 0) {
#pragma unroll
            for (int mi = 0; mi < 4; ++mi) {
#pragma unroll
                for (int ni = 0; ni < 4; ++ni) {
                    int ch = ncb + nw0 + ni * 16 + lx;
                    int h = ch >> 6, d = ch & 63;
                    float bb = bq[ch];
#pragma unroll
                    for (int r = 0; r < 4; ++r) {
                        int m = (blk & 31) * 128 + mw0 + mi * 16 + quad * 4 + r;
                        int b = m >> 10, nn = m & 1023;
                        qb[(size_t)(b * 8 + h) * 65536 + (size_t)nn * 64 + d] =
                            f2bf((acc[mi][ni][r] + bb) * 0.125f);
                    }
                }
            }
        } else if (wsel == 1) {
#pragma unroll
            for (int mi = 0; mi < 4; ++mi) {
#pragma unroll
                for (int ni = 0; ni < 4; ++ni) {
                    int ch = ncb + nw0 + ni * 16 + lx;
                    int h = ch >> 6, d = ch & 63;
#pragma unroll
                    for (int r = 0; r < 4; ++r) {
                        int m = (blk & 31) * 128 + mw0 + mi * 16 + quad * 4 + r;
                        int b = m >> 10, nn = m & 1023;
                        kb[(size_t)(b * 8 + h) * 65536 + (size_t)nn * 64 + d] =
                            f2bf(acc[mi][ni][r]);
                    }
                }
            }
        } else if (wsel == 2) {
#pragma unroll
            for (int mi = 0; mi < 4; ++mi) {
#pragma unroll
                for (int ni = 0; ni < 4; ++ni) {
                    int ch = ncb + nw0 + ni * 16 + lx;
                    float bb = bg[ch] + gbias[ch];
#pragma unroll
                    for (int r = 0; r < 4; ++r) {
                        int m = (blk & 31) * 128 + mw0 + mi * 16 + quad * 4 + r;
                        float z = acc[mi][ni][r] + bb;
                        gateb[(size_t)m * 512 + ch] = 1.f / (1.f + __expf(-z));
                    }
                }
            }
        } else {
#pragma unroll
            for (int mi = 0; mi < 4; ++mi) {
                int tok0 = (blk & 31) * 128 + mw0 + mi * 16 + quad * 4;
                int b = tok0 >> 10, nn0 = tok0 & 1023;
#pragma unroll
                for (int ni = 0; ni < 4; ++ni) {
                    int ch = ncb + nw0 + ni * 16 + lx;
                    int h = ch >> 6, d = ch & 63;
                    ushort4 u;
                    u.x = f2bf(acc[mi][ni][0]);
                    u.y = f2bf(acc[mi][ni][1]);
                    u.z = f2bf(acc[mi][ni][2]);
                    u.w = f2bf(acc[mi][ni][3]);
                    *(ushort4*)&vtb[(size_t)(b * 8 + h) * 65536 + (size_t)d * 1024 + nn0] = u;
                }
            }
        }
    }
    grid.sync();

    // ---------------- Phase 2: flash attention ----------------
    {
        unsigned short* QPs = smem;             // 64*72 (Q then P)
        unsigned short* Ks  = smem + 64 * LSTR;
        unsigned short* Vt  = smem + 128 * LSTR;
        const int bh = blk >> 4;
        const int qr0 = (blk & 15) * 64;
        const int qw0 = wid * 16;

        const unsigned short* qp = qb + (size_t)bh * 65536;
        const unsigned short* kp = kb + (size_t)bh * 65536;
        const unsigned short* vp = vtb + (size_t)bh * 65536;
        const float* bp = bias + (size_t)bh * 1048576;

        const int sr0 = tid >> 3, sc0 = (tid & 7) * 8;
        const int sr1 = (tid + 256) >> 3, sc1 = (tid & 7) * 8;

        *(float4*)&QPs[sr0 * LSTR + sc0] = *(const float4*)&qp[(size_t)(qr0 + sr0) * 64 + sc0];
        *(float4*)&QPs[sr1 * LSTR + sc1] = *(const float4*)&qp[(size_t)(qr0 + sr1) * 64 + sc1];

        float4 kr0 = *(const float4*)&kp[(size_t)sr0 * 64 + sc0];
        float4 kr1 = *(const float4*)&kp[(size_t)sr1 * 64 + sc1];
        float4 vr0 = *(const float4*)&vp[(size_t)sr0 * 1024 + sc0];
        float4 vr1 = *(const float4*)&vp[(size_t)sr1 * 1024 + sc1];

        const float* bbase = bp + (size_t)(qr0 + qw0 + quad * 4) * 1024 + lx;
        float bv[4][4];
#pragma unroll
        for (int r = 0; r < 4; ++r)
#pragma unroll
            for (int c = 0; c < 4; ++c)
                bv[r][c] = bbase[(size_t)r * 1024 + c * 16];

        __syncthreads();

        bf16x8 aq0 = ldb8(&QPs[(qw0 + lx) * LSTR + quad * 8]);
        bf16x8 aq1 = ldb8(&QPs[(qw0 + lx) * LSTR + 32 + quad * 8]);

        float l_i[4] = {0.f, 0.f, 0.f, 0.f};
        f32x4 oacc[4];
#pragma unroll
        for (int c = 0; c < 4; ++c) oacc[c] = (f32x4){0.f, 0.f, 0.f, 0.f};

#pragma unroll 1
        for (int kt = 0; kt < 16; ++kt) {
            __syncthreads();
            *(float4*)&Ks[sr0 * LSTR + sc0] = kr0;
            *(float4*)&Ks[sr1 * LSTR + sc1] = kr1;
            *(float4*)&Vt[sr0 * LSTR + sc0] = vr0;
            *(float4*)&Vt[sr1 * LSTR + sc1] = vr1;
            __syncthreads();

            const int ktn = (kt + 1) & 15;
            kr0 = *(const float4*)&kp[(size_t)(ktn * 64 + sr0) * 64 + sc0];
            kr1 = *(const float4*)&kp[(size_t)(ktn * 64 + sr1) * 64 + sc1];
            vr0 = *(const float4*)&vp[(size_t)sr0 * 1024 + ktn * 64 + sc0];
            vr1 = *(const float4*)&vp[(size_t)sr1 * 1024 + ktn * 64 + sc1];
            float bvn[4][4];
#pragma unroll
            for (int r = 0; r < 4; ++r)
#pragma unroll
                for (int c = 0; c < 4; ++c)
                    bvn[r][c] = bbase[(size_t)r * 1024 + ktn * 64 + c * 16];

            f32x4 sacc[4];
#pragma unroll
            for (int c = 0; c < 4; ++c) {
                bf16x8 bk0 = ldb8(&Ks[(c * 16 + lx) * LSTR + quad * 8]);
                bf16x8 bk1 = ldb8(&Ks[(c * 16 + lx) * LSTR + 32 + quad * 8]);
                f32x4 z = {0.f, 0.f, 0.f, 0.f};
                z = __builtin_amdgcn_mfma_f32_16x16x32_bf16(aq0, bk0, z, 0, 0, 0);
                z = __builtin_amdgcn_mfma_f32_16x16x32_bf16(aq1, bk1, z, 0, 0, 0);
                sacc[c] = z;
            }

#pragma unroll
            for (int r = 0; r < 4; ++r) {
                float p0 = __expf(sacc[0][r] + bv[r][0]);
                float p1 = __expf(sacc[1][r] + bv[r][1]);
                float p2 = __expf(sacc[2][r] + bv[r][2]);
                float p3 = __expf(sacc[3][r] + bv[r][3]);
                l_i[r] += p0 + p1 + p2 + p3;
                int prow = (qw0 + quad * 4 + r) * LSTR;
                QPs[prow + 0 * 16 + lx] = f2bf(p0);
                QPs[prow + 1 * 16 + lx] = f2bf(p1);
                QPs[prow + 2 * 16 + lx] = f2bf(p2);
                QPs[prow + 3 * 16 + lx] = f2bf(p3);
            }

            bf16x8 ap0 = ldb8(&QPs[(qw0 + lx) * LSTR + quad * 8]);
            bf16x8 ap1 = ldb8(&QPs[(qw0 + lx) * LSTR + 32 + quad * 8]);
#pragma unroll
            for (int c = 0; c < 4; ++c) {
                bf16x8 bv0 = ldb8(&Vt[(c * 16 + lx) * LSTR + quad * 8]);
                bf16x8 bv1 = ldb8(&Vt[(c * 16 + lx) * LSTR + 32 + quad * 8]);
                oacc[c] = __builtin_amdgcn_mfma_f32_16x16x32_bf16(ap0, bv0, oacc[c], 0, 0, 0);
                oacc[c] = __builtin_amdgcn_mfma_f32_16x16x32_bf16(ap1, bv1, oacc[c], 0, 0, 0);
            }

#pragma unroll
            for (int r = 0; r < 4; ++r)
#pragma unroll
                for (int c = 0; c < 4; ++c)
                    bv[r][c] = bvn[r][c];
        }

        const int b = bh >> 3, h = bh & 7;
#pragma unroll
        for (int r = 0; r < 4; ++r) {
            float lt = l_i[r];
            lt += __shfl_xor(lt, 1);
            lt += __shfl_xor(lt, 2);
            lt += __shfl_xor(lt, 4);
            lt += __shfl_xor(lt, 8);
            float inv = 1.f / lt;
            int row = qr0 + qw0 + quad * 4 + r;
            unsigned short* op = obb + (size_t)(b * 1024 + row) * 512 + h * 64 + lx;
#pragma unroll
            for (int c = 0; c < 4; ++c)
                op[c * 16] = f2bf(oacc[c][r] * inv);
        }
    }
    grid.sync();

    // ---------------- Phase 3: out GEMM 64x64 + gate ----------------
    {
        unsigned short* Ab = smem;              // 64*40
        unsigned short* Bb = smem + 64 * GSTR;  // 64*40
        const int row0 = (blk & 63) * 64;
        const int n0 = (blk >> 6) * 64;
        const unsigned short* Ag = obb + (size_t)row0 * 512;
        const unsigned short* Bg = Wcat + (size_t)(2048 + n0) * 512;
        const int mw = wid * 16;
        const int rA = tid >> 2, cA = (tid & 3) * 8;
        const int l0 = rA * GSTR + cA;

        f32x4 acc[4];
#pragma unroll
        for (int j = 0; j < 4; ++j) acc[j] = (f32x4){0.f, 0.f, 0.f, 0.f};

        float4 a0 = *(const float4*)&Ag[(size_t)rA * 512 + cA];
        float4 b0 = *(const float4*)&Bg[(size_t)rA * 512 + cA];

#pragma unroll 1
        for (int k0 = 0; k0 < 512; k0 += 32) {
            *(float4*)&Ab[l0] = a0;
            *(float4*)&Bb[l0] = b0;
            __syncthreads();
            if (k0 < 480) {
                int kn = k0 + 32;
                a0 = *(const float4*)&Ag[(size_t)rA * 512 + kn + cA];
                b0 = *(const float4*)&Bg[(size_t)rA * 512 + kn + cA];
            }
            bf16x8 af = ldb8(&Ab[(mw + lx) * GSTR + quad * 8]);
            bf16x8 bfr[4];
#pragma unroll
            for (int ni = 0; ni < 4; ++ni)
                bfr[ni] = ldb8(&Bb[(ni * 16 + lx) * GSTR + quad * 8]);
#pragma unroll
            for (int ni = 0; ni < 4; ++ni)
                acc[ni] = __builtin_amdgcn_mfma_f32_16x16x32_bf16(
                    af, bfr[ni], acc[ni], 0, 0, 0);
            __syncthreads();
        }

#pragma unroll
        for (int ni = 0; ni < 4; ++ni) {
            int n = n0 + ni * 16 + lx;
            float bb = bo[n];
#pragma unroll
            for (int r = 0; r < 4; ++r) {
                int m = row0 + mw + quad * 4 + r;
                out[(size_t)m * 512 + n] =
                    (acc[ni][r] + bb) * gateb[(size_t)m * 512 + n];
            }
        }
    }
}

// ===========================================================================
// Fallback path: R5's separate kernels (used only if cooperative occupancy
// check fails).
// ===========================================================================
__global__ __launch_bounds__(256) void convert_kernel(
    const float* __restrict__ X, const float* __restrict__ Wq,
    const float* __restrict__ Wk, const float* __restrict__ Wg,
    const float* __restrict__ Wv, const float* __restrict__ Wo,
    unsigned short* __restrict__ Xb, unsigned short* __restrict__ Wcat)
{
    int i4 = (blockIdx.x * 256 + threadIdx.x) * 4;
    const float* src;
    unsigned short* dst;
    int off;
    if (i4 < 2097152) {
        src = X; dst = Xb; off = i4;
    } else {
        int g = i4 - 2097152;
        int sect = g >> 18;
        src = (sect == 0) ? Wq : (sect == 1) ? Wk : (sect == 2) ? Wg
            : (sect == 3) ? Wv : Wo;
        dst = Wcat + (sect << 18);
        off = g & 262143;
    }
    float4 v = *(const float4*)&src[off];
    ushort4 u;
    u.x = f2bf(v.x); u.y = f2bf(v.y); u.z = f2bf(v.z); u.w = f2bf(v.w);
    *(ushort4*)&dst[off] = u;
}

__device__ __forceinline__ void gemm_core(
    const unsigned short* __restrict__ Ag, const unsigned short* __restrict__ Bg,
    unsigned short* __restrict__ Ab, unsigned short* __restrict__ Bb,
    f32x4 acc[4][4])
{
    const int tid = threadIdx.x;
    const int lane = tid & 63;
    const int quad = lane >> 4, lx = lane & 15;
    const int wid = tid >> 6;
    const int mw0 = (wid >> 1) * 64, nw0 = (wid & 1) * 64;
    const int rA = tid >> 2, cA = (tid & 3) * 8;
    const int l0 = rA * GSTR + cA;
    const int l1 = (rA + 64) * GSTR + cA;

    float4 a0 = *(const float4*)&Ag[(size_t)rA * 512 + cA];
    float4 a1 = *(const float4*)&Ag[(size_t)(rA + 64) * 512 + cA];
    float4 b0 = *(const float4*)&Bg[(size_t)rA * 512 + cA];
    float4 b1 = *(const float4*)&Bg[(size_t)(rA + 64) * 512 + cA];

#pragma unroll 1
    for (int k0 = 0; k0 < 512; k0 += 32) {
        *(float4*)&Ab[l0] = a0;
        *(float4*)&Ab[l1] = a1;
        *(float4*)&Bb[l0] = b0;
        *(float4*)&Bb[l1] = b1;
        __syncthreads();
        if (k0 < 480) {
            int kn = k0 + 32;
            a0 = *(const float4*)&Ag[(size_t)rA * 512 + kn + cA];
            a1 = *(const float4*)&Ag[(size_t)(rA + 64) * 512 + kn + cA];
            b0 = *(const float4*)&Bg[(size_t)rA * 512 + kn + cA];
            b1 = *(const float4*)&Bg[(size_t)(rA + 64) * 512 + kn + cA];
        }
        bf16x8 af[4], bfr[4];
#pragma unroll
        for (int mi = 0; mi < 4; ++mi)
            af[mi] = ldb8(&Ab[(mw0 + mi * 16 + lx) * GSTR + quad * 8]);
#pragma unroll
        for (int ni = 0; ni < 4; ++ni)
            bfr[ni] = ldb8(&Bb[(nw0 + ni * 16 + lx) * GSTR + quad * 8]);
#pragma unroll
        for (int mi = 0; mi < 4; ++mi)
#pragma unroll
            for (int ni = 0; ni < 4; ++ni)
                acc[mi][ni] = __builtin_amdgcn_mfma_f32_16x16x32_bf16(
                    af[mi], bfr[ni], acc[mi][ni], 0, 0, 0);
        __syncthreads();
    }
}

__global__ __launch_bounds__(256) void proj_gemm(
    const unsigned short* __restrict__ Xb, const unsigned short* __restrict__ Wcat,
    const float* __restrict__ bq, const float* __restrict__ bg,
    const float* __restrict__ gbias,
    unsigned short* __restrict__ qb, unsigned short* __restrict__ kb,
    unsigned short* __restrict__ vtb, float* __restrict__ gateb)
{
    __shared__ __align__(16) unsigned short Ab[128 * GSTR];
    __shared__ __align__(16) unsigned short Bb[128 * GSTR];
    const int row0 = blockIdx.x * 128;
    const int colv0 = blockIdx.y * 128;
    f32x4 acc[4][4];
#pragma unroll
    for (int i = 0; i < 4; ++i)
#pragma unroll
        for (int j = 0; j < 4; ++j) acc[i][j] = (f32x4){0.f, 0.f, 0.f, 0.f};

    gemm_core(Xb + (size_t)row0 * 512, Wcat + (size_t)colv0 * 512, Ab, Bb, acc);

    const int tid = threadIdx.x;
    const int lane = tid & 63;
    const int quad = lane >> 4, lx = lane & 15;
    const int wid = tid >> 6;
    const int mw0 = (wid >> 1) * 64, nw0 = (wid & 1) * 64;
    const int wsel = colv0 >> 9;
    const int ncb = colv0 & 511;

    if (wsel == 0) {
#pragma unroll
        for (int mi = 0; mi < 4; ++mi)
#pragma unroll
            for (int ni = 0; ni < 4; ++ni) {
                int ch = ncb + nw0 + ni * 16 + lx;
                int h = ch >> 6, d = ch & 63;
                float bb = bq[ch];
#pragma unroll
                for (int r = 0; r < 4; ++r) {
                    int m = row0 + mw0 + mi * 16 + quad * 4 + r;
                    int b = m >> 10, nn = m & 1023;
                    qb[(size_t)(b * 8 + h) * 65536 + (size_t)nn * 64 + d] =
                        f2bf((acc[mi][ni][r] + bb) * 0.125f);
                }
            }
    } else if (wsel == 1) {
#pragma unroll
        for (int mi = 0; mi < 4; ++mi)
#pragma unroll
            for (int ni = 0; ni < 4; ++ni) {
                int ch = ncb + nw0 + ni * 16 + lx;
                int h = ch >> 6, d = ch & 63;
#pragma unroll
                for (int r = 0; r < 4; ++r) {
                    int m = row0 + mw0 + mi * 16 + quad * 4 + r;
                    int b = m >> 10, nn = m & 1023;
                    kb[(size_t)(b * 8 + h) * 65536 + (size_t)nn * 64 + d] =
                        f2bf(acc[mi][ni][r]);
                }
            }
    } else if (wsel == 2) {
#pragma unroll
        for (int mi = 0; mi < 4; ++mi)
#pragma unroll
            for (int ni = 0; ni < 4; ++ni) {
                int ch = ncb + nw0 + ni * 16 + lx;
                float bb = bg[ch] + gbias[ch];
#pragma unroll
                for (int r = 0; r < 4; ++r) {
                    int m = row0 + mw0 + mi * 16 + quad * 4 + r;
                    float z = acc[mi][ni][r] + bb;
                    gateb[(size_t)m * 512 + ch] = 1.f / (1.f + __expf(-z));
                }
            }
    } else {
#pragma unroll
        for (int mi = 0; mi < 4; ++mi) {
            int tok0 = row0 + mw0 + mi * 16 + quad * 4;
            int b = tok0 >> 10, nn0 = tok0 & 1023;
#pragma unroll
            for (int ni = 0; ni < 4; ++ni) {
                int ch = ncb + nw0 + ni * 16 + lx;
                int h = ch >> 6, d = ch & 63;
                ushort4 u;
                u.x = f2bf(acc[mi][ni][0]);
                u.y = f2bf(acc[mi][ni][1]);
                u.z = f2bf(acc[mi][ni][2]);
                u.w = f2bf(acc[mi][ni][3]);
                *(ushort4*)&vtb[(size_t)(b * 8 + h) * 65536 + (size_t)d * 1024 + nn0] = u;
            }
        }
    }
}

__global__ __launch_bounds__(256) void attn_kernel(
    const unsigned short* __restrict__ qb, const unsigned short* __restrict__ kb,
    const unsigned short* __restrict__ vtb, const float* __restrict__ bias,
    unsigned short* __restrict__ obb)
{
    __shared__ unsigned short QPs[64 * LSTR];
    __shared__ unsigned short Ks[64 * LSTR];
    __shared__ unsigned short Vt[64 * LSTR];

    const int tid = threadIdx.x;
    const int bh = blockIdx.y;
    const int qr0 = blockIdx.x * 64;
    const int wv = tid >> 6, lane = tid & 63;
    const int quad = lane >> 4, lx = lane & 15;
    const int qw0 = wv * 16;

    const unsigned short* qp = qb + (size_t)bh * 65536;
    const unsigned short* kp = kb + (size_t)bh * 65536;
    const unsigned short* vp = vtb + (size_t)bh * 65536;
    const float* bp = bias + (size_t)bh * 1048576;

    const int sr0 = tid >> 3, sc0 = (tid & 7) * 8;
    const int sr1 = (tid + 256) >> 3, sc1 = (tid & 7) * 8;

    *(float4*)&QPs[sr0 * LSTR + sc0] = *(const float4*)&qp[(size_t)(qr0 + sr0) * 64 + sc0];
    *(float4*)&QPs[sr1 * LSTR + sc1] = *(const float4*)&qp[(size_t)(qr0 + sr1) * 64 + sc1];

    float4 kr0 = *(const float4*)&kp[(size_t)sr0 * 64 + sc0];
    float4 kr1 = *(const float4*)&kp[(size_t)sr1 * 64 + sc1];
    float4 vr0 = *(const float4*)&vp[(size_t)sr0 * 1024 + sc0];
    float4 vr1 = *(const float4*)&vp[(size_t)sr1 * 1024 + sc1];

    const float* bbase = bp + (size_t)(qr0 + qw0 + quad * 4) * 1024 + lx;
    float bv[4][4];
#pragma unroll
    for (int r = 0; r < 4; ++r)
#pragma unroll
        for (int c = 0; c < 4; ++c)
            bv[r][c] = bbase[(size_t)r * 1024 + c * 16];

    __syncthreads();

    bf16x8 aq0 = ldb8(&QPs[(qw0 + lx) * LSTR + quad * 8]);
    bf16x8 aq1 = ldb8(&QPs[(qw0 + lx) * LSTR + 32 + quad * 8]);

    float l_i[4] = {0.f, 0.f, 0.f, 0.f};
    f32x4 oacc[4];
#pragma unroll
    for (int c = 0; c < 4; ++c) oacc[c] = (f32x4){0.f, 0.f, 0.f, 0.f};

#pragma unroll 1
    for (int kt = 0; kt < 16; ++kt) {
        __syncthreads();
        *(float4*)&Ks[sr0 * LSTR + sc0] = kr0;
        *(float4*)&Ks[sr1 * LSTR + sc1] = kr1;
        *(float4*)&Vt[sr0 * LSTR + sc0] = vr0;
        *(float4*)&Vt[sr1 * LSTR + sc1] = vr1;
        __syncthreads();

        const int ktn = (kt + 1) & 15;
        kr0 = *(const float4*)&kp[(size_t)(ktn * 64 + sr0) * 64 + sc0];
        kr1 = *(const float4*)&kp[(size_t)(ktn * 64 + sr1) * 64 + sc1];
        vr0 = *(const float4*)&vp[(size_t)sr0 * 1024 + ktn * 64 + sc0];
        vr1 = *(const float4*)&vp[(size_t)sr1 * 1024 + ktn * 64 + sc1];
        float bvn[4][4];
#pragma unroll
        for (int r = 0; r < 4; ++r)
#pragma unroll
            for (int c = 0; c < 4; ++c)
                bvn[r][c] = bbase[(size_t)r * 1024 + ktn * 64 + c * 16];

        f32x4 sacc[4];
#pragma unroll
        for (int c = 0; c < 4; ++c) {
            bf16x8 bk0 = ldb8(&Ks[(c * 16 + lx) * LSTR + quad * 8]);
            bf16x8 bk1 = ldb8(&Ks[(c * 16 + lx) * LSTR + 32 + quad * 8]);
            f32x4 z = {0.f, 0.f, 0.f, 0.f};
            z = __builtin_amdgcn_mfma_f32_16x16x32_bf16(aq0, bk0, z, 0, 0, 0);
            z = __builtin_amdgcn_mfma_f32_16x16x32_bf16(aq1, bk1, z, 0, 0, 0);
            sacc[c] = z;
        }

#pragma unroll
        for (int r = 0; r < 4; ++r) {
            float p0 = __expf(sacc[0][r] + bv[r][0]);
            float p1 = __expf(sacc[1][r] + bv[r][1]);
            float p2 = __expf(sacc[2][r] + bv[r][2]);
            float p3 = __expf(sacc[3][r] + bv[r][3]);
            l_i[r] += p0 + p1 + p2 + p3;
            int prow = (qw0 + quad * 4 + r) * LSTR;
            QPs[prow + 0 * 16 + lx] = f2bf(p0);
            QPs[prow + 1 * 16 + lx] = f2bf(p1);
            QPs[prow + 2 * 16 + lx] = f2bf(p2);
            QPs[prow + 3 * 16 + lx] = f2bf(p3);
        }

        bf16x8 ap0 = ldb8(&QPs[(qw0 + lx) * LSTR + quad * 8]);
        bf16x8 ap1 = ldb8(&QPs[(qw0 + lx) * LSTR + 32 + quad * 8]);
#pragma unroll
        for (int c = 0; c < 4; ++c) {
            bf16x8 bv0 = ldb8(&Vt[(c * 16 + lx) * LSTR + quad * 8]);
            bf16x8 bv1 = ldb8(&Vt[(c * 16 + lx) * LSTR + 32 + quad * 8]);
            oacc[c] = __builtin_amdgcn_mfma_f32_16x16x32_bf16(ap0, bv0, oacc[c], 0, 0, 0);
            oacc[c] = __builtin_amdgcn_mfma_f32_16x16x32_bf16(ap1, bv1, oacc[c], 0, 0, 0);
        }

#pragma unroll
        for (int r = 0; r < 4; ++r)
#pragma unroll
            for (int c = 0; c < 4; ++c)
                bv[r][c] = bvn[r][c];
    }

    const int b = bh >> 3, h = bh & 7;
#pragma unroll
    for (int r = 0; r < 4; ++r) {
        float lt = l_i[r];
        lt += __shfl_xor(lt, 1);
        lt += __shfl_xor(lt, 2);
        lt += __shfl_xor(lt, 4);
        lt += __shfl_xor(lt, 8);
        float inv = 1.f / lt;
        int row = qr0 + qw0 + quad * 4 + r;
        unsigned short* op = obb + (size_t)(b * 1024 + row) * 512 + h * 64 + lx;
#pragma unroll
        for (int c = 0; c < 4; ++c)
            op[c * 16] = f2bf(oacc[c][r] * inv);
    }
}

__global__ __launch_bounds__(256) void out_gemm(
    const unsigned short* __restrict__ A, const unsigned short* __restrict__ WoB,
    const float* __restrict__ bo, const float* __restrict__ gateb,
    float* __restrict__ out)
{
    __shared__ __align__(16) unsigned short Ab[64 * GSTR];
    __shared__ __align__(16) unsigned short Bb[128 * GSTR];
    const int tid = threadIdx.x;
    const int row0 = blockIdx.x * 64;
    const int n0 = blockIdx.y * 128;
    const unsigned short* Ag = A + (size_t)row0 * 512;
    const unsigned short* Bg = WoB + (size_t)n0 * 512;

    const int lane = tid & 63;
    const int quad = lane >> 4, lx = lane & 15;
    const int wid = tid >> 6;
    const int mw0 = (wid & 1) * 32, nw0 = (wid >> 1) * 64;
    const int rA = tid >> 2, cA = (tid & 3) * 8;
    const int lA = rA * GSTR + cA;
    const int lB1 = (rA + 64) * GSTR + cA;

    f32x4 acc[2][4];
#pragma unroll
    for (int i = 0; i < 2; ++i)
#pragma unroll
        for (int j = 0; j < 4; ++j) acc[i][j] = (f32x4){0.f, 0.f, 0.f, 0.f};

    float4 a0 = *(const float4*)&Ag[(size_t)rA * 512 + cA];
    float4 b0 = *(const float4*)&Bg[(size_t)rA * 512 + cA];
    float4 b1 = *(const float4*)&Bg[(size_t)(rA + 64) * 512 + cA];

#pragma unroll 1
    for (int k0 = 0; k0 < 512; k0 += 32) {
        *(float4*)&Ab[lA] = a0;
        *(float4*)&Bb[lA] = b0;
        *(float4*)&Bb[lB1] = b1;
        __syncthreads();
        if (k0 < 480) {
            int kn = k0 + 32;
            a0 = *(const float4*)&Ag[(size_t)rA * 512 + kn + cA];
            b0 = *(const float4*)&Bg[(size_t)rA * 512 + kn + cA];
            b1 = *(const float4*)&Bg[(size_t)(rA + 64) * 512 + kn + cA];
        }
        bf16x8 af[2], bfr[4];
#pragma unroll
        for (int mi = 0; mi < 2; ++mi)
            af[mi] = ldb8(&Ab[(mw0 + mi * 16 + lx) * GSTR + quad * 8]);
#pragma unroll
        for (int ni = 0; ni < 4; ++ni)
            bfr[ni] = ldb8(&Bb[(nw0 + ni * 16 + lx) * GSTR + quad * 8]);
#pragma unroll
        for (int mi = 0; mi < 2; ++mi)
#pragma unroll
            for (int ni = 0; ni < 4; ++ni)
                acc[mi][ni] = __builtin_amdgcn_mfma_f32_16x16x32_bf16(
                    af[mi], bfr[ni], acc[mi][ni], 0, 0, 0);
        __syncthreads();
    }

#pragma unroll
    for (int mi = 0; mi < 2; ++mi)
#pragma unroll
        for (int ni = 0; ni < 4; ++ni) {
            int n = n0 + nw0 + ni * 16 + lx;
            float bb = bo[n];
#pragma unroll
            for (int r = 0; r < 4; ++r) {
                int m = row0 + mw0 + mi * 16 + quad * 4 + r;
                out[(size_t)m * 512 + n] =
                    (acc[mi][ni][r] + bb) * gateb[(size_t)m * 512 + n];
            }
        }
}

extern "C" void kernel_launch(void* const* d_in, const int* in_sizes, int n_in,
                              void* d_out, int out_size, void* d_ws, size_t ws_size,
                              hipStream_t stream) {
    (void)in_sizes; (void)n_in; (void)out_size; (void)ws_size;
    const float* q_x   = (const float*)d_in[0];
    const float* bias  = (const float*)d_in[1];
    const float* Wq    = (const float*)d_in[2];
    const float* bq    = (const float*)d_in[3];
    const float* Wk    = (const float*)d_in[4];
    const float* Wv    = (const float*)d_in[5];
    const float* Wo    = (const float*)d_in[6];
    const float* bo    = (const float*)d_in[7];
    const float* Wg    = (const float*)d_in[8];
    const float* bg    = (const float*)d_in[9];
    const float* gbias = (const float*)d_in[10];
    float* out = (float*)d_out;

    char* ws = (char*)d_ws;
    unsigned short* qb   = (unsigned short*)ws;                    // 4 MB
    unsigned short* kb   = (unsigned short*)(ws + (4u << 20));     // 4 MB
    unsigned short* vtb  = (unsigned short*)(ws + (8u << 20));     // 4 MB
    float* gateb         = (float*)(ws + (12u << 20));             // 8 MB
    unsigned short* obb  = (unsigned short*)(ws + (20u << 20));    // 4 MB
    unsigned short* Xb   = (unsigned short*)(ws + (24u << 20));    // 4 MB
    unsigned short* Wcat = (unsigned short*)(ws + (28u << 20));    // 2.5 MB

    int occ = 0;
    hipError_t e = hipOccupancyMaxActiveBlocksPerMultiprocessor(
        &occ, (const void*)fused_kernel, 256, 0);

    if (e == hipSuccess && occ >= 2) {
        void* args[] = {
            (void*)&q_x, (void*)&bias, (void*)&Wq, (void*)&bq, (void*)&Wk,
            (void*)&Wv, (void*)&Wo, (void*)&bo, (void*)&Wg, (void*)&bg,
            (void*)&gbias, (void*)&out, (void*)&qb, (void*)&kb, (void*)&vtb,
            (void*)&gateb, (void*)&obb, (void*)&Xb, (void*)&Wcat };
        hipLaunchCooperativeKernel((const void*)fused_kernel,
                                   dim3(512), dim3(256), args, 0, stream);
    } else {
        convert_kernel<<<3328, 256, 0, stream>>>(q_x, Wq, Wk, Wg, Wv, Wo, Xb, Wcat);
        proj_gemm<<<dim3(32, 16), dim3(256), 0, stream>>>(
            Xb, Wcat, bq, bg, gbias, qb, kb, vtb, gateb);
        attn_kernel<<<dim3(16, 32), dim3(256), 0, stream>>>(qb, kb, vtb, bias, obb);
        out_gemm<<<dim3(64, 4), dim3(256), 0, stream>>>(
            obb, Wcat + (size_t)2048 * 512, bo, gateb, out);
    }
}